// Round 20
// baseline (212.054 us; speedup 1.0000x reference)
//
#include <hip/hip_runtime.h>

#define NB 4
#define NH 16
#define NSQ 1024
#define NSKV 1024
#define ND 64

typedef __attribute__((ext_vector_type(8))) short short8;
typedef __attribute__((ext_vector_type(4))) float f32x4;
typedef __attribute__((ext_vector_type(4))) int int4v;
typedef __attribute__((ext_vector_type(4))) unsigned int uint4v;
typedef __attribute__((ext_vector_type(2))) unsigned int uint2v;

__device__ __forceinline__ unsigned int cvt_pk(float lo, float hi) {
  unsigned int r;
  asm("v_cvt_pk_bf16_f32 %0, %1, %2" : "=v"(r) : "v"(lo), "v"(hi));
  return r;
}
__device__ __forceinline__ float bf2f(unsigned short h) {
  return __uint_as_float(((unsigned int)h) << 16);
}
__device__ __forceinline__ void bar() { __builtin_amdgcn_s_barrier(); }
__device__ __forceinline__ void lgkm0() {
  asm volatile("s_waitcnt lgkmcnt(0)" ::: "memory");
}
// gfx950 cross-lane half-swaps (pure VALU, no LDS pipe) — R17-verified.
__device__ __forceinline__ void pl32(unsigned& a, unsigned& b) {
  asm("v_permlane32_swap_b32 %0, %1" : "+v"(a), "+v"(b));
}
__device__ __forceinline__ void pl16(unsigned& a, unsigned& b) {
  asm("v_permlane16_swap_b32 %0, %1" : "+v"(a), "+v"(b));
}

// R19 champion (symmetric balanced phases) + NONTEMPORAL STREAMING STORES:
// W and Octx outputs are never re-read -> store with nt (no L2 allocation),
// preserving XCD-L2 residency for K/V and warm A/L3 lines. All schedule and
// data-layout formulas byte-identical to R19 (verified passing, 174us).
__global__ __launch_bounds__(512, 2)
void attn_fused(const float* __restrict__ Q, const float* __restrict__ K,
                const float* __restrict__ V, const int* __restrict__ M,
                const float* __restrict__ A, float* __restrict__ Octx,
                float* __restrict__ Ow)
{
  __shared__ unsigned short Ps[64 * 1024];           // 128 KB, rows 2048B, XOR (lm<<4)
  __shared__ __align__(16) unsigned char Stg[32768]; // 2 halves x 2 bufs x 8KB

  const int t  = threadIdx.x;
  const int w  = t >> 6;
  const int l  = t & 63;
  const int lg = l >> 4;       // 0..3
  const int lm = l & 15;
  const int p  = w & 3;        // q-row pair id
  const int h  = w >> 2;       // kv half
  const int g  = p * 64 + l;   // gang lane within half (0..255)

  // XCD clustering: each bh's 16 q-tiles land on ONE XCD (K/V L2-resident)
  const int bid = blockIdx.x;            // 1024 blocks
  const int y   = bid >> 3;
  const int qt  = y & 15;                // 16 q-tiles of 64 rows
  const int bh  = (bid & 7) * 8 + (y >> 4);
  const int b   = bh >> 4;
  const int q0  = qt * 64;
  const int kvb = h * 512;

  const float* Qp = Q + (size_t)bh * NSQ * ND;
  const float* Kp = K + (size_t)bh * NSKV * ND;
  const float* Vp = V + (size_t)bh * NSKV * ND;
  const float* Ap = A + (size_t)bh * NSQ * NSKV;
  const int*   Mp = M + (size_t)b  * NSQ * NSKV;

  const float C = 0.18033688011112042f;  // 0.125 * log2(e)

  // Q fragment (B operand of QK^T): lane holds Q[q0+p*16+lm][dc*32+lg*8+e]
  short8 qf[2];
  {
    const float* qr = Qp + (size_t)(q0 + p * 16 + lm) * ND + lg * 8;
    #pragma unroll
    for (int dc = 0; dc < 2; ++dc) {
      f32x4 x = *(const f32x4*)(qr + dc * 32);
      f32x4 y2 = *(const f32x4*)(qr + dc * 32 + 4);
      uint4v u;
      u[0] = cvt_pk(x[0], x[1]); u[1] = cvt_pk(x[2], x[3]);
      u[2] = cvt_pk(y2[0], y2[1]); u[3] = cvt_pk(y2[2], y2[3]);
      qf[dc] = __builtin_bit_cast(short8, u);
    }
  }

  f32x4 ctx[4];
  #pragma unroll
  for (int i = 0; i < 4; ++i) ctx[i] = (f32x4){0.f, 0.f, 0.f, 0.f};
  float sum = 0.f;

  f32x4 sk[2], sv[2];            // staging regs: one 32-kv chunk in flight
  f32x4 aA[2], aB[2];            // A (mask+scale folded), alternating buffers

  // chunk = 32 kv x 64 d = 2048 f32 contiguous; gang lane g: g*4 + i*1024
  auto issueStage = [&](int c) {
    int kv0 = kvb + c * 32;
    const float* kb = Kp + (size_t)kv0 * ND + g * 4;
    const float* vb = Vp + (size_t)kv0 * ND + g * 4;
    sk[0] = *(const f32x4*)kb;       sk[1] = *(const f32x4*)(kb + 1024);
    sv[0] = *(const f32x4*)vb;       sv[1] = *(const f32x4*)(vb + 1024);
  };
  // A with mask fold: r[j] = m ? a*C : -1.8e8 (exp2 underflows to exact 0)
  auto loadAF = [&](int c, f32x4* a) {
    int kv0 = kvb + c * 32;
    #pragma unroll
    for (int sub = 0; sub < 2; ++sub) {
      size_t off = (size_t)(q0 + p * 16 + lm) * NSKV + kv0 + sub * 16 + lg * 4;
      f32x4 av = *(const f32x4*)(Ap + off);
      int4v mv = *(const int4v*)(Mp + off);
      f32x4 r;
      #pragma unroll
      for (int j = 0; j < 4; ++j) r[j] = mv[j] ? av[j] * C : -1.8e8f;
      a[sub] = r;
    }
  };
  auto writeStage = [&](int buf) {
    unsigned char* KsB = Stg + h * 16384 + buf * 8192;  // [32][128B] XOR (row&7)<<4
    unsigned char* VtB = KsB + 4096;                    // [64 d][64B] XOR ((d>>1)&3)<<4
    #pragma unroll
    for (int i = 0; i < 2; ++i) {
      int f = g * 4 + i * 1024;
      int row = f >> 6;            // kv-local 0..31
      int cb  = (f & 63) * 2;      // byte col in 128B row (8B-aligned)
      uint2v u;
      u[0] = cvt_pk(sk[i][0], sk[i][1]);
      u[1] = cvt_pk(sk[i][2], sk[i][3]);
      *(uint2v*)(KsB + row * 128 + (cb ^ ((row & 7) << 4))) = u;
      // V: in-register 4x4 transpose (R17-verified butterfly) across lanes
      // {l,l+16,l+32,l+48}; post: reg j = V[kvbase+j][4x+m], one b64 write.
      unsigned r0 = __float_as_uint(sv[i][0]);
      unsigned r1 = __float_as_uint(sv[i][1]);
      unsigned r2 = __float_as_uint(sv[i][2]);
      unsigned r3 = __float_as_uint(sv[i][3]);
      pl32(r0, r2); pl32(r1, r3);
      pl16(r0, r1); pl16(r2, r3);
      int d = 4 * (l & 15) + (l >> 4);
      int kvbase = 4 * p + 16 * i;
      uint2v vu;
      vu[0] = cvt_pk(__uint_as_float(r0), __uint_as_float(r1));
      vu[1] = cvt_pk(__uint_as_float(r2), __uint_as_float(r3));
      *(uint2v*)(VtB + d * 64 + ((kvbase * 2) ^ (((d >> 1) & 3) << 4))) = vu;
    }
  };

  auto compute = [&](int c, int buf, const f32x4* a) {
    const unsigned char* KsB = Stg + h * 16384 + buf * 8192;
    const unsigned char* VtB = KsB + 4096;
    int kv0 = kvb + c * 32;
    const int ksw = (lm & 7) << 4;
    const int vsw = ((lm >> 1) & 3) << 4;
    short8 kf[4];
    #pragma unroll
    for (int sub = 0; sub < 2; ++sub)
      #pragma unroll
      for (int dc = 0; dc < 2; ++dc)
        kf[sub * 2 + dc] = *(const short8*)(
            KsB + (sub * 16 + lm) * 128 + ((dc * 64 + lg * 16) ^ ksw));
    short8 vf[4];
    #pragma unroll
    for (int ds = 0; ds < 4; ++ds)
      vf[ds] = *(const short8*)(VtB + (ds * 16 + lm) * 64 + ((lg * 16) ^ vsw));

    __builtin_amdgcn_s_setprio(1);
    // QK^T (A=K,B=Q): acc[j] = logit(q=lm, kv=kv0+sub*16+lg*4+j)
    unsigned s0, s1, s2, s3;
    {
      f32x4 acc = (f32x4){0.f, 0.f, 0.f, 0.f};
      acc = __builtin_amdgcn_mfma_f32_16x16x32_bf16(kf[0], qf[0], acc, 0, 0, 0);
      acc = __builtin_amdgcn_mfma_f32_16x16x32_bf16(kf[1], qf[1], acc, 0, 0, 0);
      float pe[4];
      #pragma unroll
      for (int j = 0; j < 4; ++j) {
        pe[j] = exp2f(fmaf(acc[j], C, a[0][j]));   // masked -> exact 0
        sum += pe[j];
      }
      s0 = cvt_pk(pe[0], pe[1]); s1 = cvt_pk(pe[2], pe[3]);
      uint2v u2; u2[0] = s0; u2[1] = s1;
      *(uint2v*)((char*)Ps + (p * 16 + lm) * 2048 +
                 (((kv0 + lg * 4) * 2) ^ (lm << 4))) = u2;
    }
    {
      f32x4 acc = (f32x4){0.f, 0.f, 0.f, 0.f};
      acc = __builtin_amdgcn_mfma_f32_16x16x32_bf16(kf[2], qf[0], acc, 0, 0, 0);
      acc = __builtin_amdgcn_mfma_f32_16x16x32_bf16(kf[3], qf[1], acc, 0, 0, 0);
      float pe[4];
      #pragma unroll
      for (int j = 0; j < 4; ++j) {
        pe[j] = exp2f(fmaf(acc[j], C, a[1][j]));
        sum += pe[j];
      }
      s2 = cvt_pk(pe[0], pe[1]); s3 = cvt_pk(pe[2], pe[3]);
      uint2v u2; u2[0] = s2; u2[1] = s3;
      *(uint2v*)((char*)Ps + (p * 16 + lm) * 2048 +
                 (((kv0 + 16 + lg * 4) * 2) ^ (lm << 4))) = u2;
    }
    // pf via permlane redistribution (R17-verified; no Ps read-back)
    pl32(s0, s2); pl32(s1, s3);
    pl16(s0, s2); pl16(s1, s3);
    uint4v pu; pu[0] = s0; pu[1] = s1; pu[2] = s2; pu[3] = s3;
    short8 pf = __builtin_bit_cast(short8, pu);
    #pragma unroll
    for (int ds = 0; ds < 4; ++ds)
      ctx[ds] = __builtin_amdgcn_mfma_f32_16x16x32_bf16(pf, vf[ds], ctx[ds], 0, 0, 0);
    __builtin_amdgcn_s_setprio(0);
  };

  // ---- prologue: buf0 <- chunk0; chunk1 + A0/A1 in flight ----
  issueStage(0);
  loadAF(0, aA);
  writeStage(0);                 // vmcnt wait on chunk0 loads
  issueStage(1);                 // chunk1 loads in flight
  loadAF(1, aB);
  lgkm0(); bar();

  // ---- symmetric sweep: 16 chunks of 32 kv per half, 1 barrier/chunk ----
  for (int c = 0; c < 16; c += 2) {
    int n2 = (c + 2 > 15) ? 15 : c + 2;
    int n3 = (c + 3 > 15) ? 15 : c + 3;
    // interval A: stage chunk c+1 -> buf1 ; compute chunk c from buf0
    writeStage(1);               // sk holds chunk c+1 (counted vmcnt)
    issueStage(n2);              // chunk c+2 loads in flight
    compute(c, 0, aA);
    loadAF(n2, aA);              // consumed 2 intervals later
    lgkm0(); bar();
    // interval B: stage chunk c+2 -> buf0 ; compute chunk c+1 from buf1
    writeStage(0);               // sk holds chunk c+2
    issueStage(n3);
    compute(c + 1, 1, aB);
    loadAF(n3, aB);
    lgkm0(); bar();
  }

  // ---- merge halves (staging regions dead after this barrier) ----
  sum += __shfl_xor(sum, 16);
  sum += __shfl_xor(sum, 32);
  __syncthreads();

  float (*SumS)[2]      = (float(*)[2])Stg;                 // 64x2 overlay
  float (*CtxS)[16][64] = (float(*)[16][64])(Stg + 1024);   // 4x16x64 overlay
  if (lg == 0) SumS[p * 16 + lm][h] = sum;
  if (h == 1) {
    #pragma unroll
    for (int ds = 0; ds < 4; ++ds)
      #pragma unroll
      for (int j = 0; j < 4; ++j)
        CtxS[p][lg * 4 + j][ds * 16 + lm] = ctx[ds][j];
  }
  __syncthreads();

  if (h == 0) {
    float rcpj[4];
    #pragma unroll
    for (int j = 0; j < 4; ++j) {
      int r = p * 16 + lg * 4 + j;
      rcpj[j] = 1.0f / (SumS[r][0] + SumS[r][1]);
    }
    #pragma unroll
    for (int ds = 0; ds < 4; ++ds)
      #pragma unroll
      for (int j = 0; j < 4; ++j)
        __builtin_nontemporal_store(
            (ctx[ds][j] + CtxS[p][lg * 4 + j][ds * 16 + lm]) * rcpj[j],
            &Octx[((size_t)bh * NSQ + q0 + p * 16 + lg * 4 + j) * ND + ds * 16 + lm]);
  }

  // ---- weights out (nontemporal): wave writes 16 rows x its 512-kv half ----
  float* Owp = Ow + (size_t)bh * NSQ * NSKV + (size_t)(q0 + p * 16) * NSKV;
  for (int r = 0; r < 16; ++r) {
    float rr = 1.0f / (SumS[p * 16 + r][0] + SumS[p * 16 + r][1]);
    int kv = kvb + l * 8;
    short8 pv = *(const short8*)((char*)Ps + (p * 16 + r) * 2048 +
                                 ((kv * 2) ^ (r << 4)));
    f32x4 o1, o2;
    o1[0] = bf2f((unsigned short)pv[0]) * rr;
    o1[1] = bf2f((unsigned short)pv[1]) * rr;
    o1[2] = bf2f((unsigned short)pv[2]) * rr;
    o1[3] = bf2f((unsigned short)pv[3]) * rr;
    o2[0] = bf2f((unsigned short)pv[4]) * rr;
    o2[1] = bf2f((unsigned short)pv[5]) * rr;
    o2[2] = bf2f((unsigned short)pv[6]) * rr;
    o2[3] = bf2f((unsigned short)pv[7]) * rr;
    __builtin_nontemporal_store(o1, (f32x4*)&Owp[(size_t)r * NSKV + kv]);
    __builtin_nontemporal_store(o2, (f32x4*)&Owp[(size_t)r * NSKV + kv + 4]);
  }
}

extern "C" void kernel_launch(void* const* d_in, const int* in_sizes, int n_in,
                              void* d_out, int out_size, void* d_ws, size_t ws_size,
                              hipStream_t stream) {
  const float* Q = (const float*)d_in[0];
  const float* K = (const float*)d_in[1];
  const float* V = (const float*)d_in[2];
  const int*   M = (const int*)d_in[3];
  const float* A = (const float*)d_in[4];
  float* ctx = (float*)d_out;
  float* wts = ctx + (size_t)NB * NH * NSQ * ND;  // outputs: (context, weights)
  dim3 grid(NB * NH * (NSQ / 64));                // 1024 blocks
  attn_fused<<<grid, dim3(512), 0, stream>>>(Q, K, V, M, A, ctx, wts);
}

// Round 21
// 169.347 us; speedup vs baseline: 1.2522x; 1.2522x over previous
//
#include <hip/hip_runtime.h>

#define NB 4
#define NH 16
#define NSQ 1024
#define NSKV 1024
#define ND 64

typedef __attribute__((ext_vector_type(8))) short short8;
typedef __attribute__((ext_vector_type(4))) float f32x4;
typedef __attribute__((ext_vector_type(4))) int int4v;
typedef __attribute__((ext_vector_type(4))) unsigned int uint4v;
typedef __attribute__((ext_vector_type(2))) unsigned int uint2v;

__device__ __forceinline__ unsigned int cvt_pk(float lo, float hi) {
  unsigned int r;
  asm("v_cvt_pk_bf16_f32 %0, %1, %2" : "=v"(r) : "v"(lo), "v"(hi));
  return r;
}
__device__ __forceinline__ float bf2f(unsigned short h) {
  return __uint_as_float(((unsigned int)h) << 16);
}
__device__ __forceinline__ void bar() { __builtin_amdgcn_s_barrier(); }
__device__ __forceinline__ void lgkm0() {
  asm volatile("s_waitcnt lgkmcnt(0)" ::: "memory");
}
// gfx950 cross-lane half-swaps (pure VALU, no LDS pipe) — R17-verified.
__device__ __forceinline__ void pl32(unsigned& a, unsigned& b) {
  asm("v_permlane32_swap_b32 %0, %1" : "+v"(a), "+v"(b));
}
__device__ __forceinline__ void pl16(unsigned& a, unsigned& b) {
  asm("v_permlane16_swap_b32 %0, %1" : "+v"(a), "+v"(b));
}

// Pre-pass: compress int32 mask (1 useful bit / 32) to a bitmask.
// 16.8MB -> 512KB (L2-resident). Wave reads 64 consecutive ints,
// ballot -> u64, lane 0 stores. Bit l of word i = (M[i*64+l] != 0).
__global__ __launch_bounds__(256)
void compress_mask(const int* __restrict__ M, unsigned long long* __restrict__ Mc) {
  size_t i = (size_t)blockIdx.x * 256 + threadIdx.x;
  unsigned long long bal = __ballot(M[i] != 0);
  if ((threadIdx.x & 63) == 0) Mc[i >> 6] = bal;
}

// R19 champion (symmetric balanced phases, 174us) + COMPRESSED MASK:
// M read as ONE broadcast u32 per chunk per lane-row (vs 2x16B int4v) --
// removes 16KB/interval/CU of L2 traffic + 2 vmem issues/wave/interval and
// stops M from competing with K/V/A in L2. Stores back to NORMAL (R20
// showed nt stores amplify writes 1.4x on gfx950). All schedule and
// data-layout formulas byte-identical to R19 (verified passing).
__global__ __launch_bounds__(512, 2)
void attn_fused(const float* __restrict__ Q, const float* __restrict__ K,
                const float* __restrict__ V, const unsigned* __restrict__ Mc,
                const float* __restrict__ A, float* __restrict__ Octx,
                float* __restrict__ Ow)
{
  __shared__ unsigned short Ps[64 * 1024];           // 128 KB, rows 2048B, XOR (lm<<4)
  __shared__ __align__(16) unsigned char Stg[32768]; // 2 halves x 2 bufs x 8KB

  const int t  = threadIdx.x;
  const int w  = t >> 6;
  const int l  = t & 63;
  const int lg = l >> 4;       // 0..3
  const int lm = l & 15;
  const int p  = w & 3;        // q-row pair id
  const int h  = w >> 2;       // kv half
  const int g  = p * 64 + l;   // gang lane within half (0..255)

  // XCD clustering: each bh's 16 q-tiles land on ONE XCD (K/V L2-resident)
  const int bid = blockIdx.x;            // 1024 blocks
  const int y   = bid >> 3;
  const int qt  = y & 15;                // 16 q-tiles of 64 rows
  const int bh  = (bid & 7) * 8 + (y >> 4);
  const int b   = bh >> 4;
  const int q0  = qt * 64;
  const int kvb = h * 512;

  const float* Qp = Q + (size_t)bh * NSQ * ND;
  const float* Kp = K + (size_t)bh * NSKV * ND;
  const float* Vp = V + (size_t)bh * NSKV * ND;
  const float* Ap = A + (size_t)bh * NSQ * NSKV;
  const unsigned* Mp = Mc + ((size_t)b * NSQ) * (NSKV / 32);

  const float C = 0.18033688011112042f;  // 0.125 * log2(e)

  // Q fragment (B operand of QK^T): lane holds Q[q0+p*16+lm][dc*32+lg*8+e]
  short8 qf[2];
  {
    const float* qr = Qp + (size_t)(q0 + p * 16 + lm) * ND + lg * 8;
    #pragma unroll
    for (int dc = 0; dc < 2; ++dc) {
      f32x4 x = *(const f32x4*)(qr + dc * 32);
      f32x4 y2 = *(const f32x4*)(qr + dc * 32 + 4);
      uint4v u;
      u[0] = cvt_pk(x[0], x[1]); u[1] = cvt_pk(x[2], x[3]);
      u[2] = cvt_pk(y2[0], y2[1]); u[3] = cvt_pk(y2[2], y2[3]);
      qf[dc] = __builtin_bit_cast(short8, u);
    }
  }

  f32x4 ctx[4];
  #pragma unroll
  for (int i = 0; i < 4; ++i) ctx[i] = (f32x4){0.f, 0.f, 0.f, 0.f};
  float sum = 0.f;

  f32x4 sk[2], sv[2];            // staging regs: one 32-kv chunk in flight
  f32x4 aA[2], aB[2];            // A (mask+scale folded), alternating buffers

  // chunk = 32 kv x 64 d = 2048 f32 contiguous; gang lane g: g*4 + i*1024
  auto issueStage = [&](int c) {
    int kv0 = kvb + c * 32;
    const float* kb = Kp + (size_t)kv0 * ND + g * 4;
    const float* vb = Vp + (size_t)kv0 * ND + g * 4;
    sk[0] = *(const f32x4*)kb;       sk[1] = *(const f32x4*)(kb + 1024);
    sv[0] = *(const f32x4*)vb;       sv[1] = *(const f32x4*)(vb + 1024);
  };
  // A with mask fold from the bit word: one broadcast u32 covers the whole
  // 32-kv chunk for this lane's q-row. r[j] = bit ? a*C : -1.8e8
  auto loadAF = [&](int c, f32x4* a) {
    int kv0 = kvb + c * 32;
    unsigned mw = Mp[(size_t)(q0 + p * 16 + lm) * (NSKV / 32) + (kv0 >> 5)];
    #pragma unroll
    for (int sub = 0; sub < 2; ++sub) {
      size_t off = (size_t)(q0 + p * 16 + lm) * NSKV + kv0 + sub * 16 + lg * 4;
      f32x4 av = *(const f32x4*)(Ap + off);
      f32x4 r;
      #pragma unroll
      for (int j = 0; j < 4; ++j)
        r[j] = ((mw >> (sub * 16 + lg * 4 + j)) & 1u) ? av[j] * C : -1.8e8f;
      a[sub] = r;
    }
  };
  auto writeStage = [&](int buf) {
    unsigned char* KsB = Stg + h * 16384 + buf * 8192;  // [32][128B] XOR (row&7)<<4
    unsigned char* VtB = KsB + 4096;                    // [64 d][64B] XOR ((d>>1)&3)<<4
    #pragma unroll
    for (int i = 0; i < 2; ++i) {
      int f = g * 4 + i * 1024;
      int row = f >> 6;            // kv-local 0..31
      int cb  = (f & 63) * 2;      // byte col in 128B row (8B-aligned)
      uint2v u;
      u[0] = cvt_pk(sk[i][0], sk[i][1]);
      u[1] = cvt_pk(sk[i][2], sk[i][3]);
      *(uint2v*)(KsB + row * 128 + (cb ^ ((row & 7) << 4))) = u;
      // V: in-register 4x4 transpose (R17-verified butterfly) across lanes
      // {l,l+16,l+32,l+48}; post: reg j = V[kvbase+j][4x+m], one b64 write.
      unsigned r0 = __float_as_uint(sv[i][0]);
      unsigned r1 = __float_as_uint(sv[i][1]);
      unsigned r2 = __float_as_uint(sv[i][2]);
      unsigned r3 = __float_as_uint(sv[i][3]);
      pl32(r0, r2); pl32(r1, r3);
      pl16(r0, r1); pl16(r2, r3);
      int d = 4 * (l & 15) + (l >> 4);
      int kvbase = 4 * p + 16 * i;
      uint2v vu;
      vu[0] = cvt_pk(__uint_as_float(r0), __uint_as_float(r1));
      vu[1] = cvt_pk(__uint_as_float(r2), __uint_as_float(r3));
      *(uint2v*)(VtB + d * 64 + ((kvbase * 2) ^ (((d >> 1) & 3) << 4))) = vu;
    }
  };

  auto compute = [&](int c, int buf, const f32x4* a) {
    const unsigned char* KsB = Stg + h * 16384 + buf * 8192;
    const unsigned char* VtB = KsB + 4096;
    int kv0 = kvb + c * 32;
    const int ksw = (lm & 7) << 4;
    const int vsw = ((lm >> 1) & 3) << 4;
    short8 kf[4];
    #pragma unroll
    for (int sub = 0; sub < 2; ++sub)
      #pragma unroll
      for (int dc = 0; dc < 2; ++dc)
        kf[sub * 2 + dc] = *(const short8*)(
            KsB + (sub * 16 + lm) * 128 + ((dc * 64 + lg * 16) ^ ksw));
    short8 vf[4];
    #pragma unroll
    for (int ds = 0; ds < 4; ++ds)
      vf[ds] = *(const short8*)(VtB + (ds * 16 + lm) * 64 + ((lg * 16) ^ vsw));

    __builtin_amdgcn_s_setprio(1);
    // QK^T (A=K,B=Q): acc[j] = logit(q=lm, kv=kv0+sub*16+lg*4+j)
    unsigned s0, s1, s2, s3;
    {
      f32x4 acc = (f32x4){0.f, 0.f, 0.f, 0.f};
      acc = __builtin_amdgcn_mfma_f32_16x16x32_bf16(kf[0], qf[0], acc, 0, 0, 0);
      acc = __builtin_amdgcn_mfma_f32_16x16x32_bf16(kf[1], qf[1], acc, 0, 0, 0);
      float pe[4];
      #pragma unroll
      for (int j = 0; j < 4; ++j) {
        pe[j] = exp2f(fmaf(acc[j], C, a[0][j]));   // masked -> exact 0
        sum += pe[j];
      }
      s0 = cvt_pk(pe[0], pe[1]); s1 = cvt_pk(pe[2], pe[3]);
      uint2v u2; u2[0] = s0; u2[1] = s1;
      *(uint2v*)((char*)Ps + (p * 16 + lm) * 2048 +
                 (((kv0 + lg * 4) * 2) ^ (lm << 4))) = u2;
    }
    {
      f32x4 acc = (f32x4){0.f, 0.f, 0.f, 0.f};
      acc = __builtin_amdgcn_mfma_f32_16x16x32_bf16(kf[2], qf[0], acc, 0, 0, 0);
      acc = __builtin_amdgcn_mfma_f32_16x16x32_bf16(kf[3], qf[1], acc, 0, 0, 0);
      float pe[4];
      #pragma unroll
      for (int j = 0; j < 4; ++j) {
        pe[j] = exp2f(fmaf(acc[j], C, a[1][j]));
        sum += pe[j];
      }
      s2 = cvt_pk(pe[0], pe[1]); s3 = cvt_pk(pe[2], pe[3]);
      uint2v u2; u2[0] = s2; u2[1] = s3;
      *(uint2v*)((char*)Ps + (p * 16 + lm) * 2048 +
                 (((kv0 + 16 + lg * 4) * 2) ^ (lm << 4))) = u2;
    }
    // pf via permlane redistribution (R17-verified; no Ps read-back)
    pl32(s0, s2); pl32(s1, s3);
    pl16(s0, s2); pl16(s1, s3);
    uint4v pu; pu[0] = s0; pu[1] = s1; pu[2] = s2; pu[3] = s3;
    short8 pf = __builtin_bit_cast(short8, pu);
    #pragma unroll
    for (int ds = 0; ds < 4; ++ds)
      ctx[ds] = __builtin_amdgcn_mfma_f32_16x16x32_bf16(pf, vf[ds], ctx[ds], 0, 0, 0);
    __builtin_amdgcn_s_setprio(0);
  };

  // ---- prologue: buf0 <- chunk0; chunk1 + A0/A1 in flight ----
  issueStage(0);
  loadAF(0, aA);
  writeStage(0);                 // vmcnt wait on chunk0 loads
  issueStage(1);                 // chunk1 loads in flight
  loadAF(1, aB);
  lgkm0(); bar();

  // ---- symmetric sweep: 16 chunks of 32 kv per half, 1 barrier/chunk ----
  for (int c = 0; c < 16; c += 2) {
    int n2 = (c + 2 > 15) ? 15 : c + 2;
    int n3 = (c + 3 > 15) ? 15 : c + 3;
    // interval A: stage chunk c+1 -> buf1 ; compute chunk c from buf0
    writeStage(1);               // sk holds chunk c+1 (counted vmcnt)
    issueStage(n2);              // chunk c+2 loads in flight
    compute(c, 0, aA);
    loadAF(n2, aA);              // consumed 2 intervals later
    lgkm0(); bar();
    // interval B: stage chunk c+2 -> buf0 ; compute chunk c+1 from buf1
    writeStage(0);               // sk holds chunk c+2
    issueStage(n3);
    compute(c + 1, 1, aB);
    loadAF(n3, aB);
    lgkm0(); bar();
  }

  // ---- merge halves (staging regions dead after this barrier) ----
  sum += __shfl_xor(sum, 16);
  sum += __shfl_xor(sum, 32);
  __syncthreads();

  float (*SumS)[2]      = (float(*)[2])Stg;                 // 64x2 overlay
  float (*CtxS)[16][64] = (float(*)[16][64])(Stg + 1024);   // 4x16x64 overlay
  if (lg == 0) SumS[p * 16 + lm][h] = sum;
  if (h == 1) {
    #pragma unroll
    for (int ds = 0; ds < 4; ++ds)
      #pragma unroll
      for (int j = 0; j < 4; ++j)
        CtxS[p][lg * 4 + j][ds * 16 + lm] = ctx[ds][j];
  }
  __syncthreads();

  if (h == 0) {
    float rcpj[4];
    #pragma unroll
    for (int j = 0; j < 4; ++j) {
      int r = p * 16 + lg * 4 + j;
      rcpj[j] = 1.0f / (SumS[r][0] + SumS[r][1]);
    }
    #pragma unroll
    for (int ds = 0; ds < 4; ++ds)
      #pragma unroll
      for (int j = 0; j < 4; ++j)
        Octx[((size_t)bh * NSQ + q0 + p * 16 + lg * 4 + j) * ND + ds * 16 + lm] =
            (ctx[ds][j] + CtxS[p][lg * 4 + j][ds * 16 + lm]) * rcpj[j];
  }

  // ---- weights out: wave writes its own 16 rows x its 512-kv half ----
  float* Owp = Ow + (size_t)bh * NSQ * NSKV + (size_t)(q0 + p * 16) * NSKV;
  for (int r = 0; r < 16; ++r) {
    float rr = 1.0f / (SumS[p * 16 + r][0] + SumS[p * 16 + r][1]);
    int kv = kvb + l * 8;
    short8 pv = *(const short8*)((char*)Ps + (p * 16 + r) * 2048 +
                                 ((kv * 2) ^ (r << 4)));
    f32x4 o1, o2;
    o1[0] = bf2f((unsigned short)pv[0]) * rr;
    o1[1] = bf2f((unsigned short)pv[1]) * rr;
    o1[2] = bf2f((unsigned short)pv[2]) * rr;
    o1[3] = bf2f((unsigned short)pv[3]) * rr;
    o2[0] = bf2f((unsigned short)pv[4]) * rr;
    o2[1] = bf2f((unsigned short)pv[5]) * rr;
    o2[2] = bf2f((unsigned short)pv[6]) * rr;
    o2[3] = bf2f((unsigned short)pv[7]) * rr;
    *(f32x4*)&Owp[(size_t)r * NSKV + kv]     = o1;
    *(f32x4*)&Owp[(size_t)r * NSKV + kv + 4] = o2;
  }
}

extern "C" void kernel_launch(void* const* d_in, const int* in_sizes, int n_in,
                              void* d_out, int out_size, void* d_ws, size_t ws_size,
                              hipStream_t stream) {
  const float* Q = (const float*)d_in[0];
  const float* K = (const float*)d_in[1];
  const float* V = (const float*)d_in[2];
  const int*   M = (const int*)d_in[3];
  const float* A = (const float*)d_in[4];
  float* ctx = (float*)d_out;
  float* wts = ctx + (size_t)NB * NH * NSQ * ND;  // outputs: (context, weights)

  // pre-pass: compress mask int32 -> bitmask in workspace (512 KB)
  unsigned long long* Mc = (unsigned long long*)d_ws;
  int nInts = NB * NSQ * NSKV;                    // 4194304
  compress_mask<<<dim3(nInts / 256), dim3(256), 0, stream>>>(M, Mc);

  dim3 grid(NB * NH * (NSQ / 64));                // 1024 blocks
  attn_fused<<<grid, dim3(512), 0, stream>>>(Q, K, V, (const unsigned*)Mc, A,
                                             ctx, wts);
}